// Round 3
// baseline (559.147 us; speedup 1.0000x reference)
//
#include <hip/hip_runtime.h>

#define SQRT2F 1.41421356237309515f

typedef __attribute__((ext_vector_type(8))) short short8;
typedef __attribute__((ext_vector_type(4))) float floatx4;

static __device__ __forceinline__ unsigned short f2bf(float f) {
    unsigned int u = __float_as_uint(f);
    u += 0x7fffu + ((u >> 16) & 1u);   // RNE
    return (unsigned short)(u >> 16);
}

static __device__ __forceinline__ void gl_lds16(const void* g, void* l) {
    __builtin_amdgcn_global_load_lds(
        (const __attribute__((address_space(1))) unsigned int*)g,
        (__attribute__((address_space(3))) unsigned int*)l, 16, 0, 0);
}

// ---------------- kernel 1: style = lrelu(latent @ (aw/sqrt(512)).T + abias)*sqrt2 ----
__global__ void style_kernel(const float* __restrict__ latent,
                             const float* __restrict__ aw,
                             const float* __restrict__ abias,
                             float* __restrict__ style) {
    const int b = blockIdx.x;
    const int t = threadIdx.x;              // 256
    const int c = blockIdx.y * 256 + t;
    __shared__ float lat[512];
    lat[t]       = latent[b * 512 + t];
    lat[t + 256] = latent[b * 512 + t + 256];
    __syncthreads();
    const float* row = aw + (size_t)c * 512;
    float s0 = 0.f, s1 = 0.f, s2 = 0.f, s3 = 0.f;
    #pragma unroll 4
    for (int k = 0; k < 512; k += 4) {
        floatx4 r = *(const floatx4*)(row + k);
        s0 += lat[k]     * r[0];
        s1 += lat[k + 1] * r[1];
        s2 += lat[k + 2] * r[2];
        s3 += lat[k + 3] * r[3];
    }
    float s = (s0 + s1) + (s2 + s3);
    s = s * 0.04419417382415922f + abias[c];   // 1/sqrt(512)
    s = (s > 0.f ? s : 0.2f * s) * SQRT2F;
    style[b * 512 + c] = s;
}

// ---------------- kernel 2: raw weights -> bf16 [slab][tap][co][cin32]; demod[b][co] ----
__global__ void wprep_kernel(const float* __restrict__ cw,
                             const float* __restrict__ style,
                             unsigned short* __restrict__ wbf,
                             float* __restrict__ demod) {
    const int co = blockIdx.x;
    const int t = threadIdx.x;              // 256
    __shared__ float raw[4608];
    __shared__ float sty2[8192];
    __shared__ float r2[512];
    const float* row = cw + (size_t)co * 4608;     // [cin][3][3]
    for (int i = t; i < 1152; i += 256)
        ((floatx4*)raw)[i] = ((const floatx4*)row)[i];
    for (int i = t; i < 2048; i += 256) {
        floatx4 v = ((const floatx4*)style)[i];
        ((floatx4*)sty2)[i] = v * v;
    }
    __syncthreads();
    for (int cin = t; cin < 512; cin += 256) {
        float s = 0.f;
        #pragma unroll
        for (int tap = 0; tap < 9; ++tap) { float v = raw[cin * 9 + tap]; s += v * v; }
        r2[cin] = s;
    }
    // packed bf16 writes: 144 (slab,tap) x 4 chunks, one short8 (16B) store each
    for (int j = t; j < 576; j += 256) {
        int st = j >> 2, chunk = j & 3;            // st = slab*9+tap
        int slab = st / 9, tap = st - slab * 9;
        int cb = slab * 32 + chunk * 8;
        short8 o;
        #pragma unroll
        for (int k = 0; k < 8; ++k) o[k] = (short)f2bf(raw[(cb + k) * 9 + tap]);
        *(short8*)(wbf + ((size_t)st * 512 + co) * 32 + chunk * 8) = o;
    }
    __syncthreads();
    const int lane = t & 63, wv = t >> 6;
    #pragma unroll
    for (int bb = 0; bb < 4; ++bb) {
        int b = wv * 4 + bb;
        float s = 0.f;
        for (int cin = lane; cin < 512; cin += 64) s += r2[cin] * sty2[b * 512 + cin];
        #pragma unroll
        for (int off = 32; off > 0; off >>= 1) s += __shfl_down(s, off, 64);
        if (lane == 0) demod[b * 512 + co] = rsqrtf(s + 1e-8f);
    }
}

// ---------------- kernel 3: x' = (x + nw*noise)*style[b,cin] -> bf16 padded NHWC-slab ----
// layout: xp[b][slab16][66h][66w][32cin]; halo rows/cols zeroed HERE (no giant memset)
__global__ void xprep_kernel(const float* __restrict__ x,
                             const float* __restrict__ noise,
                             const float* __restrict__ nwp,
                             const float* __restrict__ style,
                             unsigned short* __restrict__ xp) {
    const int h = blockIdx.x, slab = blockIdx.y, b = blockIdx.z;
    const int t = threadIdx.x;              // 256
    __shared__ float tile[32][65];
    const float nw = nwp[0];
    const int w4 = (t & 15) * 4, rh = t >> 4;      // rh 0..15
    floatx4 nz = *(const floatx4*)(noise + (size_t)b * 4096 + h * 64 + w4);
    #pragma unroll
    for (int p = 0; p < 2; ++p) {
        int cl = p * 16 + rh;
        int cin = slab * 32 + cl;
        floatx4 v = *(const floatx4*)(x + ((size_t)(b * 512 + cin)) * 4096 + h * 64 + w4);
        float sv = style[b * 512 + cin];
        #pragma unroll
        for (int j = 0; j < 4; ++j) tile[cl][w4 + j] = (v[j] + nw * nz[j]) * sv;
    }
    __syncthreads();
    unsigned short* base = xp + ((size_t)(b * 16 + slab) * 4356) * 32;
    const int w2 = t >> 2, chunk = t & 3;
    short8 o;
    #pragma unroll
    for (int j = 0; j < 8; ++j) o[j] = (short)f2bf(tile[chunk * 8 + j][w2]);
    *(short8*)(base + ((size_t)(h + 1) * 66 + (w2 + 1)) * 32 + chunk * 8) = o;
    // ---- halo zeroing ----
    short8 z = {};
    if (t < 8) {   // this row's col 0 and col 65
        int col = (t >> 2) * 65;
        *(short8*)(base + ((size_t)(h + 1) * 66 + col) * 32 + (t & 3) * 8) = z;
    }
    if (h == 0) {
        for (int i = t; i < 264; i += 256)
            *(short8*)(base + (size_t)(i >> 2) * 32 + (i & 3) * 8) = z;
    } else if (h == 63) {
        for (int i = t; i < 264; i += 256)
            *(short8*)(base + ((size_t)65 * 66 + (i >> 2)) * 32 + (i & 3) * 8) = z;
    }
}

// ---------------- kernel 4: implicit-GEMM conv; weights direct global->VGPR ----------------
// 128co x 128pix (8h x 16w) per block; K-loop: 16 cin-slabs x 3 kh-groups x 3 kw.
// LDS holds ONLY the x tile (2 x 12KB double-buffer). A-frags are coalesced 1KB global
// loads from wbf (L2/L3-hot): LDS traffic per block-slab 300KB -> 84KB. One barrier/slab.
__launch_bounds__(256, 2)
__global__ void conv_kernel(const unsigned short* __restrict__ xp,
                            const unsigned short* __restrict__ wbf,
                            const float* __restrict__ demod,
                            const float* __restrict__ bias,
                            float* __restrict__ out) {
    const int b   = blockIdx.z;
    const int co0 = blockIdx.y * 128;
    const int tr  = blockIdx.x >> 2, tc = blockIdx.x & 3;
    const int h0  = tr * 8, w0 = tc * 16;
    const int tid  = threadIdx.x;
    const int lane = tid & 63, wv = tid >> 6;
    const int wr = wv >> 1, wc = wv & 1;
    const int quad = lane >> 4, l16 = lane & 15;

    __shared__ __align__(16) unsigned short lds_x[2][6144];    // 180 pos x 32cin (+pad)

    floatx4 acc[4][4] = {};

    // ---- x-tile async staging constants (unchanged, proven) ----
    int xo[3];
    #pragma unroll
    for (int it = 0; it < 3; ++it) {
        int pos = it * 64 + (tid >> 2);
        if (pos > 179) pos = 179;                              // dup-load into never-read pad
        int r = pos / 18, c = pos - r * 18;
        int lchunk = (tid & 3) ^ ((pos >> 1) & 3);
        xo[it] = (r * 66 + c) * 64 + lchunk * 16;
    }
    const int wvb = wv * 1024;

    // ---- B fragment read offsets (shorts), swizzled ----
    int bo2[6][3];   // row r = ni+kh (0..5), col-start c = kw (0..2)
    #pragma unroll
    for (int r = 0; r < 6; ++r)
        #pragma unroll
        for (int c = 0; c < 3; ++c) {
            int pos = (wc * 4 + r) * 18 + c + l16;
            bo2[r][c] = pos * 32 + (quad ^ ((pos >> 1) & 3)) * 8;
        }

    const char* xpb = (const char*)xp + ((size_t)b * 16 * 4356 + h0 * 66 + w0) * 64;
    // A-frag base: lane l reads bytes [co*64 + quad*16 .. +15] of tap-row; a wave's 64
    // lanes cover 1024 contiguous bytes (16 co x 64B) -> perfectly coalesced 1KB load.
    const char* aB = (const char*)wbf + (size_t)(co0 + wr * 64 + l16) * 64 + quad * 16;

    // ---- prologue: slab0 x-tile into buffer 0 ----
    #pragma unroll
    for (int it = 0; it < 3; ++it)
        gl_lds16(xpb + xo[it], (char*)lds_x[0] + it * 4096 + wvb);

    for (int s = 0; s < 16; ++s) {
        __syncthreads();   // x[s] landed; buffer (s+1)&1 free for overwrite
        if (s < 15) {
            const char* gx = xpb + (size_t)(s + 1) * 278784;
            char* lx = (char*)lds_x[(s + 1) & 1];
            #pragma unroll
            for (int it = 0; it < 3; ++it)
                gl_lds16(gx + xo[it], lx + it * 4096 + wvb);
        }
        const unsigned short* xbuf = lds_x[s & 1];
        const char* aS = aB + (size_t)s * 294912;   // slab stride: 9 taps * 32768B
        short8 xf[6][3];   // register-cached x fragments, filled lazily per kh-group
        #pragma unroll
        for (int g = 0; g < 3; ++g) {
            // lazy x-fragment fill: g0 reads rows 0..3; g1 row 4; g2 row 5
            if (g == 0) {
                #pragma unroll
                for (int r = 0; r < 4; ++r)
                    #pragma unroll
                    for (int c = 0; c < 3; ++c)
                        xf[r][c] = *(const short8*)(xbuf + bo2[r][c]);
            } else {
                #pragma unroll
                for (int c = 0; c < 3; ++c)
                    xf[g + 3][c] = *(const short8*)(xbuf + bo2[g + 3][c]);
            }
            // compute: 3 taps (kw) x 16 MFMA; A-frags straight from global (L2-hot)
            #pragma unroll
            for (int tl = 0; tl < 3; ++tl) {
                short8 a[4];
                #pragma unroll
                for (int mi = 0; mi < 4; ++mi)
                    a[mi] = *(const short8*)(aS + (g * 3 + tl) * 32768 + mi * 1024);
                __builtin_amdgcn_s_setprio(1);
                #pragma unroll
                for (int mi = 0; mi < 4; ++mi)
                    #pragma unroll
                    for (int ni = 0; ni < 4; ++ni)
                        acc[mi][ni] = __builtin_amdgcn_mfma_f32_16x16x32_bf16(
                            a[mi], xf[ni + g][tl], acc[mi][ni], 0, 0, 0);
                __builtin_amdgcn_s_setprio(0);
            }
        }
    }

    // ---- epilogue: *demod + bias, leaky_relu*sqrt2 ----
    const float* dmb = demod + b * 512;
    #pragma unroll
    for (int mi = 0; mi < 4; ++mi) {
        const int cob = co0 + wr * 64 + mi * 16 + quad * 4;
        float bv[4], dv[4];
        #pragma unroll
        for (int i = 0; i < 4; ++i) { bv[i] = bias[cob + i]; dv[i] = dmb[cob + i]; }
        #pragma unroll
        for (int ni = 0; ni < 4; ++ni) {
            const int gh = h0 + wc * 4 + ni;
            const int gw = w0 + l16;
            #pragma unroll
            for (int i = 0; i < 4; ++i) {
                float v = acc[mi][ni][i] * dv[i] + bv[i];
                v = (v > 0.f ? v : 0.2f * v) * SQRT2F;
                out[(((size_t)b * 512 + cob + i) * 64 + gh) * 64 + gw] = v;
            }
        }
    }
}

extern "C" void kernel_launch(void* const* d_in, const int* in_sizes, int n_in,
                              void* d_out, int out_size, void* d_ws, size_t ws_size,
                              hipStream_t stream) {
    const float* x      = (const float*)d_in[0];
    const float* latent = (const float*)d_in[1];
    const float* noise  = (const float*)d_in[2];
    const float* aw     = (const float*)d_in[3];
    const float* abias  = (const float*)d_in[4];
    const float* cw     = (const float*)d_in[5];
    const float* nwp    = (const float*)d_in[6];
    const float* bias   = (const float*)d_in[7];
    float* out = (float*)d_out;

    float* style         = (float*)d_ws;                                      // 32 KB
    float* demod         = (float*)((char*)d_ws + 32768);                     // 32 KB
    unsigned short* wbf  = (unsigned short*)((char*)d_ws + 65536);            // 4.72 MB
    unsigned short* xp   = (unsigned short*)((char*)d_ws + 65536 + 4718592);  // 71.4 MB

    style_kernel<<<dim3(16, 2), dim3(256), 0, stream>>>(latent, aw, abias, style);
    wprep_kernel<<<dim3(512), dim3(256), 0, stream>>>(cw, style, wbf, demod);
    xprep_kernel<<<dim3(64, 16, 16), dim3(256), 0, stream>>>(x, noise, nwp, style, xp);
    conv_kernel<<<dim3(32, 4, 16), dim3(256), 0, stream>>>(xp, wbf, demod, bias, out);
}

// Round 4
// 498.615 us; speedup vs baseline: 1.1214x; 1.1214x over previous
//
#include <hip/hip_runtime.h>

#define SQRT2F 1.41421356237309515f

typedef __attribute__((ext_vector_type(8))) short short8;
typedef __attribute__((ext_vector_type(4))) float floatx4;
typedef __attribute__((ext_vector_type(4))) unsigned int uint4v;

static __device__ __forceinline__ unsigned short f2bf(float f) {
    unsigned int u = __float_as_uint(f);
    u += 0x7fffu + ((u >> 16) & 1u);   // RNE
    return (unsigned short)(u >> 16);
}

// hardware RNE pack: lo -> bits[15:0], hi -> bits[31:16]
static __device__ __forceinline__ unsigned int cvt_pk_bf16(float lo, float hi) {
    unsigned int r;
    asm("v_cvt_pk_bf16_f32 %0, %1, %2" : "=v"(r) : "v"(lo), "v"(hi));
    return r;
}

static __device__ __forceinline__ void gl_lds16(const void* g, void* l) {
    __builtin_amdgcn_global_load_lds(
        (const __attribute__((address_space(1))) unsigned int*)g,
        (__attribute__((address_space(3))) unsigned int*)l, 16, 0, 0);
}

// ---------------- kernel 1: style = lrelu(latent @ (aw/sqrt(512)).T + abias)*sqrt2 ----
__global__ void style_kernel(const float* __restrict__ latent,
                             const float* __restrict__ aw,
                             const float* __restrict__ abias,
                             float* __restrict__ style) {
    const int b = blockIdx.x;
    const int t = threadIdx.x;              // 256
    const int c = blockIdx.y * 256 + t;
    __shared__ float lat[512];
    lat[t]       = latent[b * 512 + t];
    lat[t + 256] = latent[b * 512 + t + 256];
    __syncthreads();
    const float* row = aw + (size_t)c * 512;
    float s0 = 0.f, s1 = 0.f, s2 = 0.f, s3 = 0.f;
    #pragma unroll 4
    for (int k = 0; k < 512; k += 4) {
        floatx4 r = *(const floatx4*)(row + k);
        s0 += lat[k]     * r[0];
        s1 += lat[k + 1] * r[1];
        s2 += lat[k + 2] * r[2];
        s3 += lat[k + 3] * r[3];
    }
    float s = (s0 + s1) + (s2 + s3);
    s = s * 0.04419417382415922f + abias[c];   // 1/sqrt(512)
    s = (s > 0.f ? s : 0.2f * s) * SQRT2F;
    style[b * 512 + c] = s;
}

// ---------------- kernel 2: raw weights -> bf16 [slab][tap][co][cin32]; demod[b][co] ----
__global__ void wprep_kernel(const float* __restrict__ cw,
                             const float* __restrict__ style,
                             unsigned short* __restrict__ wbf,
                             float* __restrict__ demod) {
    const int co = blockIdx.x;
    const int t = threadIdx.x;              // 256
    __shared__ float raw[4608];
    __shared__ float sty2[8192];
    __shared__ float r2[512];
    const float* row = cw + (size_t)co * 4608;     // [cin][3][3]
    for (int i = t; i < 1152; i += 256)
        ((floatx4*)raw)[i] = ((const floatx4*)row)[i];
    for (int i = t; i < 2048; i += 256) {
        floatx4 v = ((const floatx4*)style)[i];
        ((floatx4*)sty2)[i] = v * v;
    }
    __syncthreads();
    for (int cin = t; cin < 512; cin += 256) {
        float s = 0.f;
        #pragma unroll
        for (int tap = 0; tap < 9; ++tap) { float v = raw[cin * 9 + tap]; s += v * v; }
        r2[cin] = s;
    }
    // packed bf16 writes: 144 (slab,tap) x 4 chunks, one 16B store each (hw cvt_pk)
    for (int j = t; j < 576; j += 256) {
        int st = j >> 2, chunk = j & 3;            // st = slab*9+tap
        int slab = st / 9, tap = st - slab * 9;
        int cb = slab * 32 + chunk * 8;
        uint4v o;
        #pragma unroll
        for (int k = 0; k < 4; ++k)
            o[k] = cvt_pk_bf16(raw[(cb + 2 * k) * 9 + tap], raw[(cb + 2 * k + 1) * 9 + tap]);
        *(uint4v*)(wbf + ((size_t)st * 512 + co) * 32 + chunk * 8) = o;
    }
    __syncthreads();
    const int lane = t & 63, wv = t >> 6;
    #pragma unroll
    for (int bb = 0; bb < 4; ++bb) {
        int b = wv * 4 + bb;
        float s = 0.f;
        for (int cin = lane; cin < 512; cin += 64) s += r2[cin] * sty2[b * 512 + cin];
        #pragma unroll
        for (int off = 32; off > 0; off >>= 1) s += __shfl_down(s, off, 64);
        if (lane == 0) demod[b * 512 + co] = rsqrtf(s + 1e-8f);
    }
}

// ---------------- kernel 3: x' = (x + nw*noise)*style[b,cin] -> bf16 padded NHWC-slab ----
// LDS-free: each thread owns 8 cin x 1 w position; loads are 64B-segment coalesced,
// store is the same contiguous 16B pattern as before. hw cvt_pk for bf16 (RNE).
__global__ void xprep_kernel(const float* __restrict__ x,
                             const float* __restrict__ noise,
                             const float* __restrict__ nwp,
                             const float* __restrict__ style,
                             unsigned short* __restrict__ xp) {
    const int h = blockIdx.x, slab = blockIdx.y, b = blockIdx.z;
    const int t = threadIdx.x;              // 256
    const int w2 = t >> 2, chunk = t & 3;   // w position, cin-octet
    const int cb = slab * 32 + chunk * 8;
    const float nv = nwp[0] * noise[(size_t)b * 4096 + h * 64 + w2];
    float val[8];
    #pragma unroll
    for (int j = 0; j < 8; ++j) {
        float xv = x[((size_t)(b * 512 + cb + j)) * 4096 + h * 64 + w2];
        val[j] = (xv + nv) * style[b * 512 + cb + j];
    }
    uint4v o;
    #pragma unroll
    for (int k = 0; k < 4; ++k) o[k] = cvt_pk_bf16(val[2 * k], val[2 * k + 1]);
    unsigned short* base = xp + ((size_t)(b * 16 + slab) * 4356) * 32;
    *(uint4v*)(base + ((size_t)(h + 1) * 66 + (w2 + 1)) * 32 + chunk * 8) = o;
    // ---- halo zeroing ----
    uint4v z = {};
    if (t < 8) {   // this row's col 0 and col 65
        int col = (t >> 2) * 65;
        *(uint4v*)(base + ((size_t)(h + 1) * 66 + col) * 32 + (t & 3) * 8) = z;
    }
    if (h == 0) {
        for (int i = t; i < 264; i += 256)
            *(uint4v*)(base + (size_t)(i >> 2) * 32 + (i & 3) * 8) = z;
    } else if (h == 63) {
        for (int i = t; i < 264; i += 256)
            *(uint4v*)(base + ((size_t)65 * 66 + (i >> 2)) * 32 + (i & 3) * 8) = z;
    }
}

// ---------------- kernel 4: implicit-GEMM conv, async-staged, swizzled LDS ----------------
// (round-1 structure, best measured: 257us) 128co x 128pix per block; 16 slabs x 3 groups.
// x-fragments register-cached across tap groups: 54 ds_read_b128 per wave-slab.
__launch_bounds__(256, 2)
__global__ void conv_kernel(const unsigned short* __restrict__ xp,
                            const unsigned short* __restrict__ wbf,
                            const float* __restrict__ demod,
                            const float* __restrict__ bias,
                            float* __restrict__ out) {
    const int b   = blockIdx.z;
    const int co0 = blockIdx.y * 128;
    const int tr  = blockIdx.x >> 2, tc = blockIdx.x & 3;
    const int h0  = tr * 8, w0 = tc * 16;
    const int tid  = threadIdx.x;
    const int lane = tid & 63, wv = tid >> 6;
    const int wr = wv >> 1, wc = wv & 1;
    const int quad = lane >> 4, l16 = lane & 15;

    __shared__ __align__(16) unsigned short lds_x[2][6144];    // 180 pos x 32cin (+pad)
    __shared__ __align__(16) unsigned short lds_w[2][12288];   // 3 taps x 128co x 32cin

    floatx4 acc[4][4] = {};

    // ---- per-thread async staging constants ----
    int wso[6];
    #pragma unroll
    for (int it = 0; it < 6; ++it) {
        int co = (it * 64 + (tid >> 2)) & 127;
        int lchunk = (tid & 3) ^ ((co >> 1) & 3);
        wso[it] = (it >> 1) * 32768 + co * 64 + lchunk * 16;   // bytes
    }
    int xo[3];
    #pragma unroll
    for (int it = 0; it < 3; ++it) {
        int pos = it * 64 + (tid >> 2);
        if (pos > 179) pos = 179;                              // dup-load into never-read pad
        int r = pos / 18, c = pos - r * 18;
        int lchunk = (tid & 3) ^ ((pos >> 1) & 3);
        xo[it] = (r * 66 + c) * 64 + lchunk * 16;
    }
    const int wvb = wv * 1024;

    // ---- fragment read offsets (shorts) ----
    int a_off[4];
    #pragma unroll
    for (int mi = 0; mi < 4; ++mi) {
        int co = wr * 64 + mi * 16 + l16;
        a_off[mi] = co * 32 + (quad ^ ((co >> 1) & 3)) * 8;
    }
    int bo2[6][3];   // row r = ni+kh (0..5), col-start c = kw (0..2)
    #pragma unroll
    for (int r = 0; r < 6; ++r)
        #pragma unroll
        for (int c = 0; c < 3; ++c) {
            int pos = (wc * 4 + r) * 18 + c + l16;
            bo2[r][c] = pos * 32 + (quad ^ ((pos >> 1) & 3)) * 8;
        }

    const char* xpb = (const char*)xp + ((size_t)b * 16 * 4356 + h0 * 66 + w0) * 64;
    const char* wb0 = (const char*)wbf + (size_t)co0 * 64;

    // ---- prologue: slab0 x-tile + group0 weights into buffer 0 ----
    #pragma unroll
    for (int it = 0; it < 3; ++it)
        gl_lds16(xpb + xo[it], (char*)lds_x[0] + it * 4096 + wvb);
    #pragma unroll
    for (int it = 0; it < 6; ++it)
        gl_lds16(wb0 + wso[it], (char*)lds_w[0] + it * 4096 + wvb);

    for (int s = 0; s < 16; ++s) {
        short8 xf[6][3];   // register-cached x fragments, filled lazily per group
        #pragma unroll
        for (int g = 0; g < 3; ++g) {
            __syncthreads();   // drains async loads for (s,g)
            // prefetch next weight group (and next slab's x-tile during g==0)
            if (g < 2) {
                const char* gw = wb0 + s * 294912 + (g + 1) * 98304;
                char* lw = (char*)lds_w[(s + g + 1) & 1];
                #pragma unroll
                for (int it = 0; it < 6; ++it)
                    gl_lds16(gw + wso[it], lw + it * 4096 + wvb);
            } else if (s < 15) {
                const char* gw = wb0 + (s + 1) * 294912;
                char* lw = (char*)lds_w[(s + 1) & 1];
                #pragma unroll
                for (int it = 0; it < 6; ++it)
                    gl_lds16(gw + wso[it], lw + it * 4096 + wvb);
            }
            if (g == 0 && s < 15) {
                const char* gx = xpb + (size_t)(s + 1) * 278784;
                char* lx = (char*)lds_x[(s + 1) & 1];
                #pragma unroll
                for (int it = 0; it < 3; ++it)
                    gl_lds16(gx + xo[it], lx + it * 4096 + wvb);
            }
            const unsigned short* wbuf = lds_w[(s + g) & 1];
            const unsigned short* xbuf = lds_x[s & 1];
            // lazy x-fragment fill: g0 reads rows 0..3; g1 row 4; g2 row 5
            if (g == 0) {
                #pragma unroll
                for (int r = 0; r < 4; ++r)
                    #pragma unroll
                    for (int c = 0; c < 3; ++c)
                        xf[r][c] = *(const short8*)(xbuf + bo2[r][c]);
            } else {
                #pragma unroll
                for (int c = 0; c < 3; ++c)
                    xf[g + 3][c] = *(const short8*)(xbuf + bo2[g + 3][c]);
            }
            // compute: 3 taps (kw) x 16 MFMA per wave; kh == g
            #pragma unroll
            for (int tl = 0; tl < 3; ++tl) {
                short8 a[4];
                #pragma unroll
                for (int mi = 0; mi < 4; ++mi)
                    a[mi] = *(const short8*)(wbuf + tl * 4096 + a_off[mi]);
                __builtin_amdgcn_s_setprio(1);
                #pragma unroll
                for (int mi = 0; mi < 4; ++mi)
                    #pragma unroll
                    for (int ni = 0; ni < 4; ++ni)
                        acc[mi][ni] = __builtin_amdgcn_mfma_f32_16x16x32_bf16(
                            a[mi], xf[ni + g][tl], acc[mi][ni], 0, 0, 0);
                __builtin_amdgcn_s_setprio(0);
            }
        }
    }

    // ---- epilogue: *demod + bias, leaky_relu*sqrt2 ----
    const float* dmb = demod + b * 512;
    #pragma unroll
    for (int mi = 0; mi < 4; ++mi) {
        const int cob = co0 + wr * 64 + mi * 16 + quad * 4;
        float bv[4], dv[4];
        #pragma unroll
        for (int i = 0; i < 4; ++i) { bv[i] = bias[cob + i]; dv[i] = dmb[cob + i]; }
        #pragma unroll
        for (int ni = 0; ni < 4; ++ni) {
            const int gh = h0 + wc * 4 + ni;
            const int gw = w0 + l16;
            #pragma unroll
            for (int i = 0; i < 4; ++i) {
                float v = acc[mi][ni][i] * dv[i] + bv[i];
                v = (v > 0.f ? v : 0.2f * v) * SQRT2F;
                out[(((size_t)b * 512 + cob + i) * 64 + gh) * 64 + gw] = v;
            }
        }
    }
}

extern "C" void kernel_launch(void* const* d_in, const int* in_sizes, int n_in,
                              void* d_out, int out_size, void* d_ws, size_t ws_size,
                              hipStream_t stream) {
    const float* x      = (const float*)d_in[0];
    const float* latent = (const float*)d_in[1];
    const float* noise  = (const float*)d_in[2];
    const float* aw     = (const float*)d_in[3];
    const float* abias  = (const float*)d_in[4];
    const float* cw     = (const float*)d_in[5];
    const float* nwp    = (const float*)d_in[6];
    const float* bias   = (const float*)d_in[7];
    float* out = (float*)d_out;

    float* style         = (float*)d_ws;                                      // 32 KB
    float* demod         = (float*)((char*)d_ws + 32768);                     // 32 KB
    unsigned short* wbf  = (unsigned short*)((char*)d_ws + 65536);            // 4.72 MB
    unsigned short* xp   = (unsigned short*)((char*)d_ws + 65536 + 4718592);  // 71.4 MB

    style_kernel<<<dim3(16, 2), dim3(256), 0, stream>>>(latent, aw, abias, style);
    wprep_kernel<<<dim3(512), dim3(256), 0, stream>>>(cw, style, wbf, demod);
    xprep_kernel<<<dim3(64, 16, 16), dim3(256), 0, stream>>>(x, noise, nwp, style, xp);
    conv_kernel<<<dim3(32, 4, 16), dim3(256), 0, stream>>>(xp, wbf, demod, bias, out);
}